// Round 3
// baseline (15047.609 us; speedup 1.0000x reference)
//
#include <hip/hip_runtime.h>
#include <hip/hip_bf16.h>

typedef __hip_bfloat16 bf16;

#define B_SZ 2
#define L_SEQ 512
#define VOCAB 512
#define D_MODEL 768
#define N_LAYERS 12
#define D_STATE 16
#define D_CONV 4
#define D_INNER 1536
#define DT_RANK 48
#define M_ROWS 1024
#define XDBL_C 80

#define BM 64
#define BN 64
#define BK 16

__device__ __forceinline__ float silu_f(float x) {
    return x / (1.f + expf(-x));
}

__device__ __forceinline__ float ld_a(const void* A, int a_bf16, size_t idx) {
    return a_bf16 ? __bfloat162float(((const bf16*)A)[idx])
                  : ((const float*)A)[idx];
}

// C[M,N] = A[M,K(lda)] * W[N,K]^T (+bias) (+addsrc) (act 1 = softplus)
// A is fp32 or bf16 (a_bf16); output -> Cf (fp32) or Cb (bf16)
__global__ __launch_bounds__(256) void gemm_tn(
    const void* __restrict__ A, int lda, int a_bf16,
    const float* __restrict__ W,
    const float* __restrict__ bias,
    const float* addsrc,
    float* Cf, bf16* Cb,
    int M, int N, int K, int act)
{
    int m0 = blockIdx.y * BM, n0 = blockIdx.x * BN;
    __shared__ float As[BK][BM];
    __shared__ float Ws[BK][BN];
    int t = threadIdx.x;
    int tx = t % 16, ty = t / 16;
    float acc[4][4] = {};
    for (int k0 = 0; k0 < K; k0 += BK) {
        for (int i = t; i < BM * BK; i += 256) {
            int r = i / BK, c = i % BK;
            int m = m0 + r, k = k0 + c;
            As[c][r] = (m < M && k < K) ? ld_a(A, a_bf16, (size_t)m * lda + k) : 0.f;
        }
        for (int i = t; i < BN * BK; i += 256) {
            int r = i / BK, c = i % BK;
            int n = n0 + r, k = k0 + c;
            Ws[c][r] = (n < N && k < K) ? W[(size_t)n * K + k] : 0.f;
        }
        __syncthreads();
#pragma unroll
        for (int k = 0; k < BK; ++k) {
            float a[4], b[4];
#pragma unroll
            for (int i = 0; i < 4; i++) a[i] = As[k][ty * 4 + i];
#pragma unroll
            for (int j = 0; j < 4; j++) b[j] = Ws[k][tx * 4 + j];
#pragma unroll
            for (int i = 0; i < 4; i++)
#pragma unroll
                for (int j = 0; j < 4; j++)
                    acc[i][j] += a[i] * b[j];
        }
        __syncthreads();
    }
#pragma unroll
    for (int i = 0; i < 4; i++) {
        int m = m0 + ty * 4 + i;
        if (m >= M) continue;
#pragma unroll
        for (int j = 0; j < 4; j++) {
            int n = n0 + tx * 4 + j;
            if (n >= N) continue;
            float v = acc[i][j];
            if (bias) v += bias[n];
            if (addsrc) v += addsrc[(size_t)m * N + n];
            if (act == 1) v = (v > 20.f) ? v : log1pf(expf(v));
            if (Cb) Cb[(size_t)m * N + n] = __float2bfloat16(v);
            else    Cf[(size_t)m * N + n] = v;
        }
    }
}

__global__ __launch_bounds__(256) void embed_kernel(
    const float* __restrict__ emb, const int* __restrict__ ids,
    float* __restrict__ x)
{
    int idx = blockIdx.x * 256 + threadIdx.x;
    if (idx >= M_ROWS * D_MODEL) return;
    int m = idx / D_MODEL, k = idx % D_MODEL;
    x[idx] = emb[(size_t)ids[m] * D_MODEL + k];
}

// u = silu(conv(u_pre) + bias); u_pre stride D_INNER (bf16 in, bf16 out)
__global__ __launch_bounds__(256) void conv_silu_kernel(
    const bf16* __restrict__ upre, const float* __restrict__ w,
    const float* __restrict__ bias, bf16* __restrict__ u)
{
    int idx = blockIdx.x * 256 + threadIdx.x;
    if (idx >= M_ROWS * D_INNER) return;
    int d = idx % D_INNER;
    int m = idx / D_INNER;
    int l = m % L_SEQ;
    float acc = bias[d];
#pragma unroll
    for (int j = 0; j < D_CONV; ++j) {
        int ls = l - (D_CONV - 1) + j;
        if (ls >= 0)
            acc += w[d * D_CONV + j] *
                   __bfloat162float(upre[(size_t)(m - (D_CONV - 1) + j) * D_INNER + d]);
    }
    u[idx] = __float2bfloat16(silu_f(acc));
}

// one thread per (b,d); y written in place over u (read-then-write per step)
__global__ __launch_bounds__(256) void scan_kernel(
    const bf16* __restrict__ delta, bf16* uy,
    const float* __restrict__ xdbl, const float* __restrict__ A_log,
    const float* __restrict__ Dp)
{
    int tid = blockIdx.x * 256 + threadIdx.x;
    if (tid >= B_SZ * D_INNER) return;
    int b = tid / D_INNER, d = tid % D_INNER;
    float A[D_STATE], h[D_STATE];
#pragma unroll
    for (int n = 0; n < D_STATE; n++) {
        A[n] = -expf(A_log[d * D_STATE + n]);
        h[n] = 0.f;
    }
    float Dv = Dp[d];
    for (int l = 0; l < L_SEQ; l++) {
        int m = b * L_SEQ + l;
        float dl = __bfloat162float(delta[(size_t)m * D_INNER + d]);
        float uv = __bfloat162float(uy[(size_t)m * D_INNER + d]);
        float du = dl * uv;
        const float* bc = xdbl + (size_t)m * XDBL_C + DT_RANK;
        float yv = 0.f;
#pragma unroll
        for (int n = 0; n < D_STATE; n++) {
            h[n] = expf(dl * A[n]) * h[n] + du * bc[n];
            yv += h[n] * bc[D_STATE + n];
        }
        uy[(size_t)m * D_INNER + d] = __float2bfloat16(yv + uv * Dv);
    }
}

// g = y * silu(res), written in place over res
__global__ __launch_bounds__(256) void gate_kernel(
    const bf16* __restrict__ y, bf16* resg)
{
    int idx = blockIdx.x * 256 + threadIdx.x;
    if (idx >= M_ROWS * D_INNER) return;
    float r = __bfloat162float(resg[idx]);
    float v = __bfloat162float(y[idx]) * silu_f(r);
    resg[idx] = __float2bfloat16(v);
}

__global__ __launch_bounds__(256) void ln_kernel(
    const float* __restrict__ x, const float* __restrict__ gam,
    const float* __restrict__ bet, float* __restrict__ hidden_f32)
{
    int row = blockIdx.x;
    const float* xr = x + (size_t)row * D_MODEL;
    float s = 0.f, s2 = 0.f;
    for (int i = threadIdx.x; i < D_MODEL; i += 256) {
        float v = xr[i];
        s += v; s2 += v * v;
    }
    __shared__ float red[18];
#pragma unroll
    for (int off = 32; off; off >>= 1) {
        s += __shfl_down(s, off);
        s2 += __shfl_down(s2, off);
    }
    int wid = threadIdx.x / 64, lane = threadIdx.x % 64;
    if (lane == 0) { red[wid * 2] = s; red[wid * 2 + 1] = s2; }
    __syncthreads();
    if (threadIdx.x == 0) {
        float ts = 0.f, ts2 = 0.f;
        for (int w = 0; w < 4; w++) { ts += red[w * 2]; ts2 += red[w * 2 + 1]; }
        red[16] = ts; red[17] = ts2;
    }
    __syncthreads();
    float mean = red[16] / D_MODEL;
    float var = red[17] / D_MODEL - mean * mean;
    float inv = rsqrtf(var + 1e-5f);
    for (int i = threadIdx.x; i < D_MODEL; i += 256) {
        float v = (xr[i] - mean) * inv * gam[i] + bet[i];
        hidden_f32[(size_t)row * D_MODEL + i] = v;
    }
}

extern "C" void kernel_launch(void* const* d_in, const int* in_sizes, int n_in,
                              void* d_out, int out_size, void* d_ws, size_t ws_size,
                              hipStream_t stream) {
    const float* emb    = (const float*)d_in[0];
    const float* in_w   = (const float*)d_in[1];
    const float* conv_w = (const float*)d_in[2];
    const float* conv_b = (const float*)d_in[3];
    const float* xp_w   = (const float*)d_in[4];
    const float* dt_w   = (const float*)d_in[5];
    const float* dt_b   = (const float*)d_in[6];
    const float* A_log  = (const float*)d_in[7];
    const float* Dp     = (const float*)d_in[8];
    const float* out_w  = (const float*)d_in[9];
    const float* ln_g   = (const float*)d_in[10];
    const float* ln_b   = (const float*)d_in[11];
    const float* head_w = (const float*)d_in[12];
    const float* head_b = (const float*)d_in[13];
    const int*   ids    = (const int*)d_in[14];

    // d_out is FLOAT32 (reference output dtype): logits [1024,512] then hidden [1024,768]
    float* out_logits = (float*)d_out;
    float* out_hidden = (float*)d_out + (size_t)M_ROWS * VOCAB;

    // ws layout: x (fp32), xdbl (fp32), P/Q/R (bf16 scratch) — ~12.9 MB
    char* base = (char*)d_ws;
    float* x    = (float*)(base);                                   // 3,145,728 B
    float* xdbl = (float*)(base + 3145728);                         //   327,680 B
    bf16*  P    = (bf16*) (base + 3145728 + 327680);                // 3,145,728 B
    bf16*  Q    = (bf16*) (base + 3145728 + 327680 + 3145728);      // 3,145,728 B
    bf16*  R    = (bf16*) (base + 3145728 + 327680 + 2*3145728);    // 3,145,728 B

    const int EL = (M_ROWS * D_INNER + 255) / 256;

    embed_kernel<<<(M_ROWS * D_MODEL + 255) / 256, 256, 0, stream>>>(emb, ids, x);

    for (int i = 0; i < N_LAYERS; i++) {
        const float* in_w_i   = in_w   + (size_t)i * 2 * D_INNER * D_MODEL;
        const float* conv_w_i = conv_w + (size_t)i * D_INNER * D_CONV;
        const float* conv_b_i = conv_b + (size_t)i * D_INNER;
        const float* xp_w_i   = xp_w   + (size_t)i * XDBL_C * D_INNER;
        const float* dt_w_i   = dt_w   + (size_t)i * D_INNER * DT_RANK;
        const float* dt_b_i   = dt_b   + (size_t)i * D_INNER;
        const float* A_log_i  = A_log  + (size_t)i * D_INNER * D_STATE;
        const float* Dp_i     = Dp     + (size_t)i * D_INNER;
        const float* out_w_i  = out_w  + (size_t)i * D_MODEL * D_INNER;

        // P = u_pre = x @ in_w[0:1536]^T
        gemm_tn<<<dim3(D_INNER / BN, M_ROWS / BM), 256, 0, stream>>>(
            x, D_MODEL, 0, in_w_i, nullptr, nullptr, nullptr, P,
            M_ROWS, D_INNER, D_MODEL, 0);
        // Q = res = x @ in_w[1536:3072]^T
        gemm_tn<<<dim3(D_INNER / BN, M_ROWS / BM), 256, 0, stream>>>(
            x, D_MODEL, 0, in_w_i + (size_t)D_INNER * D_MODEL, nullptr, nullptr,
            nullptr, Q, M_ROWS, D_INNER, D_MODEL, 0);
        // R = u = silu(conv(P) + conv_b)
        conv_silu_kernel<<<EL, 256, 0, stream>>>(P, conv_w_i, conv_b_i, R);
        // xdbl = R @ xp_w^T  [1024, 80]
        gemm_tn<<<dim3(2, M_ROWS / BM), 256, 0, stream>>>(
            R, D_INNER, 1, xp_w_i, nullptr, nullptr, xdbl, nullptr,
            M_ROWS, XDBL_C, D_INNER, 0);
        // P = delta = softplus(xdbl[:, :48] @ dt_w^T + dt_b)
        gemm_tn<<<dim3(D_INNER / BN, M_ROWS / BM), 256, 0, stream>>>(
            xdbl, XDBL_C, 0, dt_w_i, dt_b_i, nullptr, nullptr, P,
            M_ROWS, D_INNER, DT_RANK, 1);
        // R = y = selective_scan(delta=P, u=R, B/C=xdbl)
        scan_kernel<<<(B_SZ * D_INNER + 255) / 256, 256, 0, stream>>>(
            P, R, xdbl, A_log_i, Dp_i);
        // Q = g = y * silu(res)
        gate_kernel<<<EL, 256, 0, stream>>>(R, Q);
        // x = Q @ out_w^T + x
        gemm_tn<<<dim3(D_MODEL / BN, M_ROWS / BM), 256, 0, stream>>>(
            Q, D_INNER, 1, out_w_i, nullptr, x, x, nullptr,
            M_ROWS, D_MODEL, D_INNER, 0);
    }

    // LN -> hidden (fp32 directly into d_out tail)
    ln_kernel<<<M_ROWS, 256, 0, stream>>>(x, ln_g, ln_b, out_hidden);

    // logits = hidden @ head_w^T + head_b -> fp32 at d_out head
    gemm_tn<<<dim3(VOCAB / BN, M_ROWS / BM), 256, 0, stream>>>(
        out_hidden, D_MODEL, 0, head_w, head_b, nullptr, out_logits, nullptr,
        M_ROWS, VOCAB, D_MODEL, 0);
}

// Round 4
// 6375.513 us; speedup vs baseline: 2.3602x; 2.3602x over previous
//
#include <hip/hip_runtime.h>
#include <hip/hip_bf16.h>

typedef __hip_bfloat16 bf16;
typedef __attribute__((ext_vector_type(8))) short short8;
typedef __attribute__((ext_vector_type(4))) float f32x4;

#define B_SZ 2
#define L_SEQ 512
#define VOCAB 512
#define D_MODEL 768
#define N_LAYERS 12
#define D_STATE 16
#define D_CONV 4
#define D_INNER 1536
#define DT_RANK 48
#define M_ROWS 1024
#define XDBL_C 80

#define GBM 64
#define GBN 64
#define GBK 32
#define LDP 40   // padded LDS row length (elements)

__device__ __forceinline__ float silu_f(float x) {
    return x / (1.f + expf(-x));
}

__device__ __forceinline__ short f2bs(float x) {
    bf16 t = __float2bfloat16(x);
    return *reinterpret_cast<short*>(&t);
}

// C[M,N] = A[M,K(lda)] * W[N,K]^T (+bias) (+addsrc) (act 1 = softplus)
// A: fp32 (a_f32=1) or bf16; W: fp32 (converted to bf16 in staging).
// Outputs optional: Cf (fp32), Cb (bf16).
// Requires: M % 64 == 0, K % 8 == 0, 16B-aligned rows for A and W.
__global__ __launch_bounds__(256) void gemm_mfma(
    const void* __restrict__ A, int lda, int a_f32,
    const float* __restrict__ W, int ldw,
    const float* __restrict__ bias,
    const float* addsrc,
    float* Cf, bf16* Cb,
    int M, int N, int K, int act)
{
    __shared__ short As[GBM * LDP];
    __shared__ short Ws[GBN * LDP];
    int t = threadIdx.x;
    int m0 = blockIdx.y * GBM, n0 = blockIdx.x * GBN;
    int wave = t >> 6, lane = t & 63;
    int wr = wave >> 1, wc = wave & 1;        // 2x2 wave grid, each 32x32
    int lrow = lane & 15, lk = lane >> 4;     // fragment row / k-group
    int srow = t >> 2, scol = (t & 3) * 8;    // staging: 64 rows x 4 chunks of 8

    f32x4 acc[2][2] = {};

    for (int k0 = 0; k0 < K; k0 += GBK) {
        // stage A tile (64 x 32)
        {
            int gk = k0 + scol;
            short8 v = {};
            if (gk < K) {
                if (a_f32) {
                    const float* p = (const float*)A + (size_t)(m0 + srow) * lda + gk;
                    float4 f0 = *(const float4*)p;
                    float4 f1 = *(const float4*)(p + 4);
                    v[0] = f2bs(f0.x); v[1] = f2bs(f0.y); v[2] = f2bs(f0.z); v[3] = f2bs(f0.w);
                    v[4] = f2bs(f1.x); v[5] = f2bs(f1.y); v[6] = f2bs(f1.z); v[7] = f2bs(f1.w);
                } else {
                    v = *(const short8*)((const bf16*)A + (size_t)(m0 + srow) * lda + gk);
                }
            }
            *(short8*)(&As[srow * LDP + scol]) = v;
        }
        // stage W tile (64 x 32), fp32 -> bf16
        {
            int gn = n0 + srow, gk = k0 + scol;
            short8 v = {};
            if (gn < N && gk < K) {
                const float* p = W + (size_t)gn * ldw + gk;
                float4 f0 = *(const float4*)p;
                float4 f1 = *(const float4*)(p + 4);
                v[0] = f2bs(f0.x); v[1] = f2bs(f0.y); v[2] = f2bs(f0.z); v[3] = f2bs(f0.w);
                v[4] = f2bs(f1.x); v[5] = f2bs(f1.y); v[6] = f2bs(f1.z); v[7] = f2bs(f1.w);
            }
            *(short8*)(&Ws[srow * LDP + scol]) = v;
        }
        __syncthreads();

        short8 af[2], bw[2];
#pragma unroll
        for (int i = 0; i < 2; i++) {
            af[i] = *(const short8*)(&As[(wr * 32 + i * 16 + lrow) * LDP + lk * 8]);
            bw[i] = *(const short8*)(&Ws[(wc * 32 + i * 16 + lrow) * LDP + lk * 8]);
        }
#pragma unroll
        for (int i = 0; i < 2; i++)
#pragma unroll
            for (int j = 0; j < 2; j++)
                acc[i][j] = __builtin_amdgcn_mfma_f32_16x16x32_bf16(af[i], bw[j], acc[i][j], 0, 0, 0);
        __syncthreads();
    }

#pragma unroll
    for (int i = 0; i < 2; i++)
#pragma unroll
        for (int j = 0; j < 2; j++) {
            int col = n0 + wc * 32 + j * 16 + lrow;
            if (col >= N) continue;
#pragma unroll
            for (int r = 0; r < 4; r++) {
                int row = m0 + wr * 32 + i * 16 + lk * 4 + r;
                float v = acc[i][j][r];
                if (bias) v += bias[col];
                if (addsrc) v += addsrc[(size_t)row * N + col];
                if (act == 1) v = (v > 20.f) ? v : log1pf(expf(v));
                if (Cf) Cf[(size_t)row * N + col] = v;
                if (Cb) Cb[(size_t)row * N + col] = __float2bfloat16(v);
            }
        }
}

__global__ __launch_bounds__(256) void embed_kernel(
    const float* __restrict__ emb, const int* __restrict__ ids,
    float* __restrict__ x)
{
    int idx = blockIdx.x * 256 + threadIdx.x;
    if (idx >= M_ROWS * D_MODEL) return;
    int m = idx / D_MODEL, k = idx % D_MODEL;
    x[idx] = emb[(size_t)ids[m] * D_MODEL + k];
}

// u = silu(conv(xr[:, :D_INNER]) + conv_b); xr stride 2*D_INNER; out bf16
__global__ __launch_bounds__(256) void conv_silu_kernel(
    const bf16* __restrict__ xr, const float* __restrict__ w,
    const float* __restrict__ bias, bf16* __restrict__ u)
{
    int idx = blockIdx.x * 256 + threadIdx.x;
    if (idx >= M_ROWS * D_INNER) return;
    int d = idx % D_INNER;
    int m = idx / D_INNER;
    int l = m % L_SEQ;
    float acc = bias[d];
#pragma unroll
    for (int j = 0; j < D_CONV; ++j) {
        int ls = l - (D_CONV - 1) + j;
        if (ls >= 0)
            acc += w[d * D_CONV + j] *
                   __bfloat162float(xr[(size_t)(m - (D_CONV - 1) + j) * (2 * D_INNER) + d]);
    }
    u[idx] = __float2bfloat16(silu_f(acc));
}

// thread per (b,d,n): 16 lanes = 16 states; shfl-reduce for y; gate fused.
// uy: in = u, out = g = y*silu(res). res read from xr[:, D_INNER+d].
__global__ __launch_bounds__(256) void scan_kernel(
    const bf16* __restrict__ delta, bf16* uy,
    const bf16* __restrict__ xr, const bf16* __restrict__ xdbl,
    const float* __restrict__ A_log, const float* __restrict__ Dp)
{
    int t = blockIdx.x * 256 + threadIdx.x;   // 49152 threads
    int n = t & 15, dg = t >> 4;
    int b = dg / D_INNER, d = dg % D_INNER;
    float An = -expf(A_log[d * D_STATE + n]);
    float Dv = Dp[d];
    float h = 0.f;
    for (int l = 0; l < L_SEQ; l++) {
        int m = b * L_SEQ + l;
        float dl = __bfloat162float(delta[(size_t)m * D_INNER + d]);
        float uv = __bfloat162float(uy[(size_t)m * D_INNER + d]);
        float Bn = __bfloat162float(xdbl[(size_t)m * XDBL_C + DT_RANK + n]);
        float Cn = __bfloat162float(xdbl[(size_t)m * XDBL_C + DT_RANK + D_STATE + n]);
        h = expf(dl * An) * h + (dl * uv) * Bn;
        float p = h * Cn;
        p += __shfl_xor(p, 1, 16);
        p += __shfl_xor(p, 2, 16);
        p += __shfl_xor(p, 4, 16);
        p += __shfl_xor(p, 8, 16);
        if (n == 0) {
            float y = p + uv * Dv;
            float r = __bfloat162float(xr[(size_t)m * (2 * D_INNER) + D_INNER + d]);
            uy[(size_t)m * D_INNER + d] = __float2bfloat16(y * silu_f(r));
        }
    }
}

__global__ __launch_bounds__(256) void ln_kernel(
    const float* __restrict__ x, const float* __restrict__ gam,
    const float* __restrict__ bet, float* __restrict__ hidden_f32)
{
    int row = blockIdx.x;
    const float* xr = x + (size_t)row * D_MODEL;
    float s = 0.f, s2 = 0.f;
    for (int i = threadIdx.x; i < D_MODEL; i += 256) {
        float v = xr[i];
        s += v; s2 += v * v;
    }
    __shared__ float red[18];
#pragma unroll
    for (int off = 32; off; off >>= 1) {
        s += __shfl_down(s, off);
        s2 += __shfl_down(s2, off);
    }
    int wid = threadIdx.x / 64, lane = threadIdx.x % 64;
    if (lane == 0) { red[wid * 2] = s; red[wid * 2 + 1] = s2; }
    __syncthreads();
    if (threadIdx.x == 0) {
        float ts = 0.f, ts2 = 0.f;
        for (int w = 0; w < 4; w++) { ts += red[w * 2]; ts2 += red[w * 2 + 1]; }
        red[16] = ts; red[17] = ts2;
    }
    __syncthreads();
    float mean = red[16] / D_MODEL;
    float var = red[17] / D_MODEL - mean * mean;
    float inv = rsqrtf(var + 1e-5f);
    for (int i = threadIdx.x; i < D_MODEL; i += 256) {
        float v = (xr[i] - mean) * inv * gam[i] + bet[i];
        hidden_f32[(size_t)row * D_MODEL + i] = v;
    }
}

extern "C" void kernel_launch(void* const* d_in, const int* in_sizes, int n_in,
                              void* d_out, int out_size, void* d_ws, size_t ws_size,
                              hipStream_t stream) {
    const float* emb    = (const float*)d_in[0];
    const float* in_w   = (const float*)d_in[1];
    const float* conv_w = (const float*)d_in[2];
    const float* conv_b = (const float*)d_in[3];
    const float* xp_w   = (const float*)d_in[4];
    const float* dt_w   = (const float*)d_in[5];
    const float* dt_b   = (const float*)d_in[6];
    const float* A_log  = (const float*)d_in[7];
    const float* Dp     = (const float*)d_in[8];
    const float* out_w  = (const float*)d_in[9];
    const float* ln_g   = (const float*)d_in[10];
    const float* ln_b   = (const float*)d_in[11];
    const float* head_w = (const float*)d_in[12];
    const float* head_b = (const float*)d_in[13];
    const int*   ids    = (const int*)d_in[14];

    float* out_logits = (float*)d_out;
    float* out_hidden = (float*)d_out + (size_t)M_ROWS * VOCAB;

    // ws: x f32 (3.15MB) | xr bf16 (6.29MB) | R bf16 (3.15MB) | dlt bf16 (3.15MB) | xdbl bf16 (0.16MB)
    char* base = (char*)d_ws;
    float* x    = (float*)(base);
    bf16*  xrב  = nullptr; (void)xrב;
    bf16*  xr   = (bf16*)(base + 3145728);
    bf16*  R    = (bf16*)(base + 3145728 + 6291456);
    bf16*  dlt  = (bf16*)(base + 3145728 + 6291456 + 3145728);
    bf16*  xdbl = (bf16*)(base + 3145728 + 6291456 + 3145728 + 3145728);

    embed_kernel<<<(M_ROWS * D_MODEL + 255) / 256, 256, 0, stream>>>(emb, ids, x);

    for (int i = 0; i < N_LAYERS; i++) {
        const float* in_w_i   = in_w   + (size_t)i * 2 * D_INNER * D_MODEL;
        const float* conv_w_i = conv_w + (size_t)i * D_INNER * D_CONV;
        const float* conv_b_i = conv_b + (size_t)i * D_INNER;
        const float* xp_w_i   = xp_w   + (size_t)i * XDBL_C * D_INNER;
        const float* dt_w_i   = dt_w   + (size_t)i * D_INNER * DT_RANK;
        const float* dt_b_i   = dt_b   + (size_t)i * D_INNER;
        const float* A_log_i  = A_log  + (size_t)i * D_INNER * D_STATE;
        const float* Dp_i     = Dp     + (size_t)i * D_INNER;
        const float* out_w_i  = out_w  + (size_t)i * D_MODEL * D_INNER;

        // xr = x @ in_w^T  [1024, 3072] bf16
        gemm_mfma<<<dim3(2 * D_INNER / GBN, M_ROWS / GBM), 256, 0, stream>>>(
            x, D_MODEL, 1, in_w_i, D_MODEL, nullptr, nullptr, nullptr, xr,
            M_ROWS, 2 * D_INNER, D_MODEL, 0);

        // R = u = silu(conv(xr[:, :1536]) + conv_b)
        conv_silu_kernel<<<(M_ROWS * D_INNER + 255) / 256, 256, 0, stream>>>(
            xr, conv_w_i, conv_b_i, R);

        // xdbl = R @ xp_w^T  [1024, 80] bf16
        gemm_mfma<<<dim3((XDBL_C + GBN - 1) / GBN, M_ROWS / GBM), 256, 0, stream>>>(
            R, D_INNER, 0, xp_w_i, D_INNER, nullptr, nullptr, nullptr, xdbl,
            M_ROWS, XDBL_C, D_INNER, 0);

        // dlt = softplus(xdbl[:, :48] @ dt_w^T + dt_b)  [1024, 1536] bf16
        gemm_mfma<<<dim3(D_INNER / GBN, M_ROWS / GBM), 256, 0, stream>>>(
            xdbl, XDBL_C, 0, dt_w_i, DT_RANK, dt_b_i, nullptr, nullptr, dlt,
            M_ROWS, D_INNER, DT_RANK, 1);

        // R <- g = scan(...) * silu(res)
        scan_kernel<<<(B_SZ * D_INNER * D_STATE) / 256, 256, 0, stream>>>(
            dlt, R, xr, xdbl, A_log_i, Dp_i);

        // x = g @ out_w^T + x  [1024, 768] fp32
        gemm_mfma<<<dim3(D_MODEL / GBN, M_ROWS / GBM), 256, 0, stream>>>(
            R, D_INNER, 0, out_w_i, D_INNER, nullptr, x, x, nullptr,
            M_ROWS, D_MODEL, D_INNER, 0);
    }

    // LN -> hidden fp32 directly into d_out tail
    ln_kernel<<<M_ROWS, 256, 0, stream>>>(x, ln_g, ln_b, out_hidden);

    // logits = hidden @ head_w^T + head_b -> fp32 at d_out head
    gemm_mfma<<<dim3(VOCAB / GBN, M_ROWS / GBM), 256, 0, stream>>>(
        out_hidden, D_MODEL, 1, head_w, D_MODEL, head_b, nullptr, out_logits, nullptr,
        M_ROWS, VOCAB, D_MODEL, 0);
}

// Round 5
// 2554.476 us; speedup vs baseline: 5.8907x; 2.4958x over previous
//
#include <hip/hip_runtime.h>
#include <hip/hip_bf16.h>

typedef __hip_bfloat16 bf16;
typedef __attribute__((ext_vector_type(8))) short short8;
typedef __attribute__((ext_vector_type(4))) float f32x4;

#define B_SZ 2
#define L_SEQ 512
#define VOCAB 512
#define D_MODEL 768
#define N_LAYERS 12
#define D_STATE 16
#define D_CONV 4
#define D_INNER 1536
#define DT_RANK 48
#define M_ROWS 1024
#define XDBL_C 80
#define NCH 16
#define CL 32

#define GBM 64
#define GBN 64
#define GBK 32
#define LDP 40   // padded LDS row length (elements)

__device__ __forceinline__ float silu_f(float x) {
    return x / (1.f + expf(-x));
}

__device__ __forceinline__ float b2f(bf16 x) { return __bfloat162float(x); }

__device__ __forceinline__ short f2bs(float x) {
    bf16 t = __float2bfloat16(x);
    return *reinterpret_cast<short*>(&t);
}

// C[M,N] = A[M,K(lda)] * W[N,K]^T (+bias) (+addsrc) (act 1 = softplus)
__global__ __launch_bounds__(256) void gemm_mfma(
    const void* __restrict__ A, int lda, int a_f32,
    const float* __restrict__ W, int ldw,
    const float* __restrict__ bias,
    const float* addsrc,
    float* Cf, bf16* Cb,
    int M, int N, int K, int act)
{
    __shared__ short As[GBM * LDP];
    __shared__ short Ws[GBN * LDP];
    int t = threadIdx.x;
    int m0 = blockIdx.y * GBM, n0 = blockIdx.x * GBN;
    int wave = t >> 6, lane = t & 63;
    int wr = wave >> 1, wc = wave & 1;
    int lrow = lane & 15, lk = lane >> 4;
    int srow = t >> 2, scol = (t & 3) * 8;

    f32x4 acc[2][2] = {};

    for (int k0 = 0; k0 < K; k0 += GBK) {
        {
            int gk = k0 + scol;
            short8 v = {};
            if (gk < K) {
                if (a_f32) {
                    const float* p = (const float*)A + (size_t)(m0 + srow) * lda + gk;
                    float4 f0 = *(const float4*)p;
                    float4 f1 = *(const float4*)(p + 4);
                    v[0] = f2bs(f0.x); v[1] = f2bs(f0.y); v[2] = f2bs(f0.z); v[3] = f2bs(f0.w);
                    v[4] = f2bs(f1.x); v[5] = f2bs(f1.y); v[6] = f2bs(f1.z); v[7] = f2bs(f1.w);
                } else {
                    v = *(const short8*)((const bf16*)A + (size_t)(m0 + srow) * lda + gk);
                }
            }
            *(short8*)(&As[srow * LDP + scol]) = v;
        }
        {
            int gn = n0 + srow, gk = k0 + scol;
            short8 v = {};
            if (gn < N && gk < K) {
                const float* p = W + (size_t)gn * ldw + gk;
                float4 f0 = *(const float4*)p;
                float4 f1 = *(const float4*)(p + 4);
                v[0] = f2bs(f0.x); v[1] = f2bs(f0.y); v[2] = f2bs(f0.z); v[3] = f2bs(f0.w);
                v[4] = f2bs(f1.x); v[5] = f2bs(f1.y); v[6] = f2bs(f1.z); v[7] = f2bs(f1.w);
            }
            *(short8*)(&Ws[srow * LDP + scol]) = v;
        }
        __syncthreads();

        short8 af[2], bw[2];
#pragma unroll
        for (int i = 0; i < 2; i++) {
            af[i] = *(const short8*)(&As[(wr * 32 + i * 16 + lrow) * LDP + lk * 8]);
            bw[i] = *(const short8*)(&Ws[(wc * 32 + i * 16 + lrow) * LDP + lk * 8]);
        }
#pragma unroll
        for (int i = 0; i < 2; i++)
#pragma unroll
            for (int j = 0; j < 2; j++)
                acc[i][j] = __builtin_amdgcn_mfma_f32_16x16x32_bf16(af[i], bw[j], acc[i][j], 0, 0, 0);
        __syncthreads();
    }

#pragma unroll
    for (int i = 0; i < 2; i++)
#pragma unroll
        for (int j = 0; j < 2; j++) {
            int col = n0 + wc * 32 + j * 16 + lrow;
            if (col >= N) continue;
#pragma unroll
            for (int r = 0; r < 4; r++) {
                int row = m0 + wr * 32 + i * 16 + lk * 4 + r;
                float v = acc[i][j][r];
                if (bias) v += bias[col];
                if (addsrc) v += addsrc[(size_t)row * N + col];
                if (act == 1) v = (v > 20.f) ? v : log1pf(expf(v));
                if (Cf) Cf[(size_t)row * N + col] = v;
                if (Cb) Cb[(size_t)row * N + col] = __float2bfloat16(v);
            }
        }
}

__global__ __launch_bounds__(256) void embed_kernel(
    const float* __restrict__ emb, const int* __restrict__ ids,
    float* __restrict__ x)
{
    int idx = blockIdx.x * 256 + threadIdx.x;
    if (idx >= M_ROWS * D_MODEL) return;
    int m = idx / D_MODEL, k = idx % D_MODEL;
    x[idx] = emb[(size_t)ids[m] * D_MODEL + k];
}

__global__ __launch_bounds__(256) void conv_silu_kernel(
    const bf16* __restrict__ xr, const float* __restrict__ w,
    const float* __restrict__ bias, bf16* __restrict__ u)
{
    int idx = blockIdx.x * 256 + threadIdx.x;
    if (idx >= M_ROWS * D_INNER) return;
    int d = idx % D_INNER;
    int m = idx / D_INNER;
    int l = m % L_SEQ;
    float acc = bias[d];
#pragma unroll
    for (int j = 0; j < D_CONV; ++j) {
        int ls = l - (D_CONV - 1) + j;
        if (ls >= 0)
            acc += w[d * D_CONV + j] *
                   b2f(xr[(size_t)(m - (D_CONV - 1) + j) * (2 * D_INNER) + d]);
    }
    u[idx] = __float2bfloat16(silu_f(acc));
}

// Chunked parallel scan: one block per (b,d). 256 threads = 16 chunks x 16 states.
// Phase A: per-chunk (P=prod a, Q=carry). Phase B: cross-chunk combine (LDS).
// Phase C: re-scan with correct h0, shfl-reduce y over n, fused gate.
// g written into xrg[:, 0:D_INNER] (stride 2*D_INNER); res read from xrg[:, D_INNER:].
__global__ __launch_bounds__(256) void scan_chunked(
    const bf16* __restrict__ delta, const bf16* __restrict__ u,
    const bf16* __restrict__ xdbl, bf16* xrg,
    const float* __restrict__ A_log, const float* __restrict__ Dp)
{
    int t = threadIdx.x;
    int n = t & 15, c = t >> 4;
    int dg = blockIdx.x;
    int b = dg / D_INNER, d = dg % D_INNER;

    __shared__ float Pl[NCH][D_STATE], Ql[NCH][D_STATE], H0[NCH][D_STATE];

    float An = -expf(A_log[d * D_STATE + n]);
    float Dv = Dp[d];
    int m0 = b * L_SEQ + c * CL;

    // Phase A
    float P = 1.f, h = 0.f;
#pragma unroll 4
    for (int i = 0; i < CL; i++) {
        size_t m = m0 + i;
        float dl = b2f(delta[m * D_INNER + d]);
        float uv = b2f(u[m * D_INNER + d]);
        float Bn = b2f(xdbl[m * XDBL_C + DT_RANK + n]);
        float a = expf(dl * An);
        P *= a;
        h = a * h + (dl * uv) * Bn;
    }
    Pl[c][n] = P; Ql[c][n] = h;
    __syncthreads();

    // Phase B: 16 threads scan across chunks
    if (t < D_STATE) {
        float h0 = 0.f;
        H0[0][t] = 0.f;
        for (int cc = 1; cc < NCH; cc++) {
            h0 = Pl[cc - 1][t] * h0 + Ql[cc - 1][t];
            H0[cc][t] = h0;
        }
    }
    __syncthreads();

    // Phase C
    h = H0[c][n];
#pragma unroll 4
    for (int i = 0; i < CL; i++) {
        size_t m = m0 + i;
        float dl = b2f(delta[m * D_INNER + d]);
        float uv = b2f(u[m * D_INNER + d]);
        float Bn = b2f(xdbl[m * XDBL_C + DT_RANK + n]);
        float Cn = b2f(xdbl[m * XDBL_C + DT_RANK + D_STATE + n]);
        float a = expf(dl * An);
        h = a * h + (dl * uv) * Bn;
        float p = h * Cn;
        p += __shfl_xor(p, 1, 16);
        p += __shfl_xor(p, 2, 16);
        p += __shfl_xor(p, 4, 16);
        p += __shfl_xor(p, 8, 16);
        if (n == 0) {
            float y = p + uv * Dv;
            float r = b2f(xrg[m * (2 * D_INNER) + D_INNER + d]);
            xrg[m * (2 * D_INNER) + d] = __float2bfloat16(y * silu_f(r));
        }
    }
}

__global__ __launch_bounds__(256) void ln_kernel(
    const float* __restrict__ x, const float* __restrict__ gam,
    const float* __restrict__ bet, float* __restrict__ hidden_f32)
{
    int row = blockIdx.x;
    const float* xr = x + (size_t)row * D_MODEL;
    float s = 0.f, s2 = 0.f;
    for (int i = threadIdx.x; i < D_MODEL; i += 256) {
        float v = xr[i];
        s += v; s2 += v * v;
    }
    __shared__ float red[18];
#pragma unroll
    for (int off = 32; off; off >>= 1) {
        s += __shfl_down(s, off);
        s2 += __shfl_down(s2, off);
    }
    int wid = threadIdx.x / 64, lane = threadIdx.x % 64;
    if (lane == 0) { red[wid * 2] = s; red[wid * 2 + 1] = s2; }
    __syncthreads();
    if (threadIdx.x == 0) {
        float ts = 0.f, ts2 = 0.f;
        for (int w = 0; w < 4; w++) { ts += red[w * 2]; ts2 += red[w * 2 + 1]; }
        red[16] = ts; red[17] = ts2;
    }
    __syncthreads();
    float mean = red[16] / D_MODEL;
    float var = red[17] / D_MODEL - mean * mean;
    float inv = rsqrtf(var + 1e-5f);
    for (int i = threadIdx.x; i < D_MODEL; i += 256) {
        float v = (xr[i] - mean) * inv * gam[i] + bet[i];
        hidden_f32[(size_t)row * D_MODEL + i] = v;
    }
}

extern "C" void kernel_launch(void* const* d_in, const int* in_sizes, int n_in,
                              void* d_out, int out_size, void* d_ws, size_t ws_size,
                              hipStream_t stream) {
    const float* emb    = (const float*)d_in[0];
    const float* in_w   = (const float*)d_in[1];
    const float* conv_w = (const float*)d_in[2];
    const float* conv_b = (const float*)d_in[3];
    const float* xp_w   = (const float*)d_in[4];
    const float* dt_w   = (const float*)d_in[5];
    const float* dt_b   = (const float*)d_in[6];
    const float* A_log  = (const float*)d_in[7];
    const float* Dp     = (const float*)d_in[8];
    const float* out_w  = (const float*)d_in[9];
    const float* ln_g   = (const float*)d_in[10];
    const float* ln_b   = (const float*)d_in[11];
    const float* head_w = (const float*)d_in[12];
    const float* head_b = (const float*)d_in[13];
    const int*   ids    = (const int*)d_in[14];

    float* out_logits = (float*)d_out;
    float* out_hidden = (float*)d_out + (size_t)M_ROWS * VOCAB;

    char* base = (char*)d_ws;
    float* x    = (float*)(base);
    bf16*  xr   = (bf16*)(base + 3145728);
    bf16*  R    = (bf16*)(base + 3145728 + 6291456);
    bf16*  dlt  = (bf16*)(base + 3145728 + 6291456 + 3145728);
    bf16*  xdbl = (bf16*)(base + 3145728 + 6291456 + 3145728 + 3145728);

    embed_kernel<<<(M_ROWS * D_MODEL + 255) / 256, 256, 0, stream>>>(emb, ids, x);

    for (int i = 0; i < N_LAYERS; i++) {
        const float* in_w_i   = in_w   + (size_t)i * 2 * D_INNER * D_MODEL;
        const float* conv_w_i = conv_w + (size_t)i * D_INNER * D_CONV;
        const float* conv_b_i = conv_b + (size_t)i * D_INNER;
        const float* xp_w_i   = xp_w   + (size_t)i * XDBL_C * D_INNER;
        const float* dt_w_i   = dt_w   + (size_t)i * D_INNER * DT_RANK;
        const float* dt_b_i   = dt_b   + (size_t)i * D_INNER;
        const float* A_log_i  = A_log  + (size_t)i * D_INNER * D_STATE;
        const float* Dp_i     = Dp     + (size_t)i * D_INNER;
        const float* out_w_i  = out_w  + (size_t)i * D_MODEL * D_INNER;

        // xr = x @ in_w^T  [1024, 3072] bf16
        gemm_mfma<<<dim3(2 * D_INNER / GBN, M_ROWS / GBM), 256, 0, stream>>>(
            x, D_MODEL, 1, in_w_i, D_MODEL, nullptr, nullptr, nullptr, xr,
            M_ROWS, 2 * D_INNER, D_MODEL, 0);

        // R = u = silu(conv(xr[:, :1536]) + conv_b)
        conv_silu_kernel<<<(M_ROWS * D_INNER + 255) / 256, 256, 0, stream>>>(
            xr, conv_w_i, conv_b_i, R);

        // xdbl = R @ xp_w^T  [1024, 80] bf16
        gemm_mfma<<<dim3((XDBL_C + GBN - 1) / GBN, M_ROWS / GBM), 256, 0, stream>>>(
            R, D_INNER, 0, xp_w_i, D_INNER, nullptr, nullptr, nullptr, xdbl,
            M_ROWS, XDBL_C, D_INNER, 0);

        // dlt = softplus(xdbl[:, :48] @ dt_w^T + dt_b)  [1024, 1536] bf16
        gemm_mfma<<<dim3(D_INNER / GBN, M_ROWS / GBM), 256, 0, stream>>>(
            xdbl, XDBL_C, 0, dt_w_i, DT_RANK, dt_b_i, nullptr, nullptr, dlt,
            M_ROWS, D_INNER, DT_RANK, 1);

        // scan + gate fused; g -> xr[:, 0:1536]
        scan_chunked<<<B_SZ * D_INNER, 256, 0, stream>>>(
            dlt, R, xdbl, xr, A_log_i, Dp_i);

        // x = g @ out_w^T + x   (A = xr cols 0..1535, lda 3072)
        gemm_mfma<<<dim3(D_MODEL / GBN, M_ROWS / GBM), 256, 0, stream>>>(
            xr, 2 * D_INNER, 0, out_w_i, D_INNER, nullptr, x, x, nullptr,
            M_ROWS, D_MODEL, D_INNER, 0);
    }

    ln_kernel<<<M_ROWS, 256, 0, stream>>>(x, ln_g, ln_b, out_hidden);

    gemm_mfma<<<dim3(VOCAB / GBN, M_ROWS / GBM), 256, 0, stream>>>(
        out_hidden, D_MODEL, 1, head_w, D_MODEL, head_b, nullptr, out_logits, nullptr,
        M_ROWS, VOCAB, D_MODEL, 0);
}

// Round 6
// 2258.602 us; speedup vs baseline: 6.6624x; 1.1310x over previous
//
#include <hip/hip_runtime.h>
#include <hip/hip_bf16.h>

typedef __hip_bfloat16 bf16;
typedef __attribute__((ext_vector_type(8))) short short8;
typedef __attribute__((ext_vector_type(4))) float f32x4;

#define B_SZ 2
#define L_SEQ 512
#define VOCAB 512
#define D_MODEL 768
#define N_LAYERS 12
#define D_STATE 16
#define D_CONV 4
#define D_INNER 1536
#define DT_RANK 48
#define M_ROWS 1024
#define XDBL_C 80

// scan geometry: 8 d-lanes x 32 chunks of 16 steps
#define SDG 8
#define SNCH 32
#define SCL 16

#define GBM 64
#define GBN 64
#define GBK 32
#define LDP 40   // padded LDS row length (elements)

__device__ __forceinline__ float silu_f(float x) {
    return x / (1.f + expf(-x));
}

__device__ __forceinline__ float b2f(bf16 x) { return __bfloat162float(x); }

__device__ __forceinline__ float bs2f(short s) {
    unsigned int v = ((unsigned int)(unsigned short)s) << 16;
    union { unsigned int u; float f; } cv; cv.u = v;
    return cv.f;
}

__device__ __forceinline__ short f2bs(float x) {
    bf16 t = __float2bfloat16(x);
    return *reinterpret_cast<short*>(&t);
}

// C[M,N] = A[M,K(lda)] * W[N,K]^T (+bias) (+addsrc) (act 1 = softplus)
__global__ __launch_bounds__(256) void gemm_mfma(
    const void* __restrict__ A, int lda, int a_f32,
    const float* __restrict__ W, int ldw,
    const float* __restrict__ bias,
    const float* addsrc,
    float* Cf, bf16* Cb,
    int M, int N, int K, int act)
{
    __shared__ short As[GBM * LDP];
    __shared__ short Ws[GBN * LDP];
    int t = threadIdx.x;
    int m0 = blockIdx.y * GBM, n0 = blockIdx.x * GBN;
    int wave = t >> 6, lane = t & 63;
    int wr = wave >> 1, wc = wave & 1;
    int lrow = lane & 15, lk = lane >> 4;
    int srow = t >> 2, scol = (t & 3) * 8;

    f32x4 acc[2][2] = {};

    for (int k0 = 0; k0 < K; k0 += GBK) {
        {
            int gk = k0 + scol;
            short8 v = {};
            if (gk < K) {
                if (a_f32) {
                    const float* p = (const float*)A + (size_t)(m0 + srow) * lda + gk;
                    float4 f0 = *(const float4*)p;
                    float4 f1 = *(const float4*)(p + 4);
                    v[0] = f2bs(f0.x); v[1] = f2bs(f0.y); v[2] = f2bs(f0.z); v[3] = f2bs(f0.w);
                    v[4] = f2bs(f1.x); v[5] = f2bs(f1.y); v[6] = f2bs(f1.z); v[7] = f2bs(f1.w);
                } else {
                    v = *(const short8*)((const bf16*)A + (size_t)(m0 + srow) * lda + gk);
                }
            }
            *(short8*)(&As[srow * LDP + scol]) = v;
        }
        {
            int gn = n0 + srow, gk = k0 + scol;
            short8 v = {};
            if (gn < N && gk < K) {
                const float* p = W + (size_t)gn * ldw + gk;
                float4 f0 = *(const float4*)p;
                float4 f1 = *(const float4*)(p + 4);
                v[0] = f2bs(f0.x); v[1] = f2bs(f0.y); v[2] = f2bs(f0.z); v[3] = f2bs(f0.w);
                v[4] = f2bs(f1.x); v[5] = f2bs(f1.y); v[6] = f2bs(f1.z); v[7] = f2bs(f1.w);
            }
            *(short8*)(&Ws[srow * LDP + scol]) = v;
        }
        __syncthreads();

        short8 af[2], bw[2];
#pragma unroll
        for (int i = 0; i < 2; i++) {
            af[i] = *(const short8*)(&As[(wr * 32 + i * 16 + lrow) * LDP + lk * 8]);
            bw[i] = *(const short8*)(&Ws[(wc * 32 + i * 16 + lrow) * LDP + lk * 8]);
        }
#pragma unroll
        for (int i = 0; i < 2; i++)
#pragma unroll
            for (int j = 0; j < 2; j++)
                acc[i][j] = __builtin_amdgcn_mfma_f32_16x16x32_bf16(af[i], bw[j], acc[i][j], 0, 0, 0);
        __syncthreads();
    }

#pragma unroll
    for (int i = 0; i < 2; i++)
#pragma unroll
        for (int j = 0; j < 2; j++) {
            int col = n0 + wc * 32 + j * 16 + lrow;
            if (col >= N) continue;
#pragma unroll
            for (int r = 0; r < 4; r++) {
                int row = m0 + wr * 32 + i * 16 + lk * 4 + r;
                float v = acc[i][j][r];
                if (bias) v += bias[col];
                if (addsrc) v += addsrc[(size_t)row * N + col];
                if (act == 1) v = (v > 20.f) ? v : log1pf(expf(v));
                if (Cf) Cf[(size_t)row * N + col] = v;
                if (Cb) Cb[(size_t)row * N + col] = __float2bfloat16(v);
            }
        }
}

__global__ __launch_bounds__(256) void embed_kernel(
    const float* __restrict__ emb, const int* __restrict__ ids,
    float* __restrict__ x)
{
    int idx = blockIdx.x * 256 + threadIdx.x;
    if (idx >= M_ROWS * D_MODEL) return;
    int m = idx / D_MODEL, k = idx % D_MODEL;
    x[idx] = emb[(size_t)ids[m] * D_MODEL + k];
}

__global__ __launch_bounds__(256) void conv_silu_kernel(
    const bf16* __restrict__ xr, const float* __restrict__ w,
    const float* __restrict__ bias, bf16* __restrict__ u)
{
    int idx = blockIdx.x * 256 + threadIdx.x;
    if (idx >= M_ROWS * D_INNER) return;
    int d = idx % D_INNER;
    int m = idx / D_INNER;
    int l = m % L_SEQ;
    float acc = bias[d];
#pragma unroll
    for (int j = 0; j < D_CONV; ++j) {
        int ls = l - (D_CONV - 1) + j;
        if (ls >= 0)
            acc += w[d * D_CONV + j] *
                   b2f(xr[(size_t)(m - (D_CONV - 1) + j) * (2 * D_INNER) + d]);
    }
    u[idx] = __float2bfloat16(silu_f(acc));
}

// Chunked parallel scan, d-per-lane layout.
// Block: 256 threads = 8 consecutive d x 32 chunks of 16 steps. Grid: B * D_INNER/8.
// Each thread owns all 16 states in registers; y = sum_n h*C computed in-register.
// g written into xrg[:, 0:D_INNER] (stride 2*D_INNER); res read from xrg[:, D_INNER:].
__global__ __launch_bounds__(256) void scan_chunked(
    const bf16* __restrict__ delta, const bf16* __restrict__ u,
    const bf16* __restrict__ xdbl, bf16* xrg,
    const float* __restrict__ A_log, const float* __restrict__ Dp)
{
    int t = threadIdx.x;
    int dl_ = t & (SDG - 1);
    int c   = t >> 3;                 // 0..31
    int bg  = blockIdx.x;
    int b   = bg / (D_INNER / SDG);
    int dg  = bg % (D_INNER / SDG);
    int d   = dg * SDG + dl_;

    __shared__ float Pl[SNCH][SDG][17];
    __shared__ float Ql[SNCH][SDG][17];

    float An[D_STATE], h[D_STATE], Pp[D_STATE];
#pragma unroll
    for (int n = 0; n < D_STATE; n++) {
        An[n] = -expf(A_log[d * D_STATE + n]);
        h[n] = 0.f;
        Pp[n] = 1.f;
    }

    int m0 = b * L_SEQ + c * SCL;

    // Phase A: per-chunk prefix (P = prod a, Q = carry h from 0)
    for (int i = 0; i < SCL; i++) {
        size_t m = m0 + i;
        float dlv = b2f(delta[m * D_INNER + d]);
        float uvv = b2f(u[m * D_INNER + d]);
        float duv = dlv * uvv;
        const short8* brow = (const short8*)((const short*)xdbl + m * XDBL_C + DT_RANK);
        short8 b0 = brow[0], b1 = brow[1];
#pragma unroll
        for (int n = 0; n < D_STATE; n++) {
            float a = expf(dlv * An[n]);
            Pp[n] *= a;
            float Bn = bs2f(n < 8 ? b0[n] : b1[n - 8]);
            h[n] = a * h[n] + duv * Bn;
        }
    }
#pragma unroll
    for (int n = 0; n < D_STATE; n++) {
        Pl[c][dl_][n] = Pp[n];
        Ql[c][dl_][n] = h[n];
    }
    __syncthreads();

    // Phase B: cross-chunk serial combine per (d, n); H0 overwrites Pl in place
    if (t < SDG * D_STATE) {
        int dd = t & (SDG - 1);
        int nn = t >> 3;
        float h0 = 0.f;
        for (int cc = 0; cc < SNCH; cc++) {
            float p = Pl[cc][dd][nn];
            float q = Ql[cc][dd][nn];
            Pl[cc][dd][nn] = h0;
            h0 = p * h0 + q;
        }
    }
    __syncthreads();

    // Phase C: re-scan from correct h0; y in-register; fused gate
    float Dv = Dp[d];
#pragma unroll
    for (int n = 0; n < D_STATE; n++) h[n] = Pl[c][dl_][n];
    for (int i = 0; i < SCL; i++) {
        size_t m = m0 + i;
        float dlv = b2f(delta[m * D_INNER + d]);
        float uvv = b2f(u[m * D_INNER + d]);
        float duv = dlv * uvv;
        const short8* brow = (const short8*)((const short*)xdbl + m * XDBL_C + DT_RANK);
        short8 b0 = brow[0], b1 = brow[1];
        const short8* crow = brow + 2;
        short8 c0 = crow[0], c1 = crow[1];
        float y = 0.f;
#pragma unroll
        for (int n = 0; n < D_STATE; n++) {
            float a = expf(dlv * An[n]);
            float Bn = bs2f(n < 8 ? b0[n] : b1[n - 8]);
            float Cn = bs2f(n < 8 ? c0[n] : c1[n - 8]);
            h[n] = a * h[n] + duv * Bn;
            y += h[n] * Cn;
        }
        y += uvv * Dv;
        float r = b2f(xrg[m * (2 * D_INNER) + D_INNER + d]);
        xrg[m * (2 * D_INNER) + d] = __float2bfloat16(y * silu_f(r));
    }
}

__global__ __launch_bounds__(256) void ln_kernel(
    const float* __restrict__ x, const float* __restrict__ gam,
    const float* __restrict__ bet, float* __restrict__ hidden_f32)
{
    int row = blockIdx.x;
    const float* xr = x + (size_t)row * D_MODEL;
    float s = 0.f, s2 = 0.f;
    for (int i = threadIdx.x; i < D_MODEL; i += 256) {
        float v = xr[i];
        s += v; s2 += v * v;
    }
    __shared__ float red[18];
#pragma unroll
    for (int off = 32; off; off >>= 1) {
        s += __shfl_down(s, off);
        s2 += __shfl_down(s2, off);
    }
    int wid = threadIdx.x / 64, lane = threadIdx.x % 64;
    if (lane == 0) { red[wid * 2] = s; red[wid * 2 + 1] = s2; }
    __syncthreads();
    if (threadIdx.x == 0) {
        float ts = 0.f, ts2 = 0.f;
        for (int w = 0; w < 4; w++) { ts += red[w * 2]; ts2 += red[w * 2 + 1]; }
        red[16] = ts; red[17] = ts2;
    }
    __syncthreads();
    float mean = red[16] / D_MODEL;
    float var = red[17] / D_MODEL - mean * mean;
    float inv = rsqrtf(var + 1e-5f);
    for (int i = threadIdx.x; i < D_MODEL; i += 256) {
        float v = (xr[i] - mean) * inv * gam[i] + bet[i];
        hidden_f32[(size_t)row * D_MODEL + i] = v;
    }
}

extern "C" void kernel_launch(void* const* d_in, const int* in_sizes, int n_in,
                              void* d_out, int out_size, void* d_ws, size_t ws_size,
                              hipStream_t stream) {
    const float* emb    = (const float*)d_in[0];
    const float* in_w   = (const float*)d_in[1];
    const float* conv_w = (const float*)d_in[2];
    const float* conv_b = (const float*)d_in[3];
    const float* xp_w   = (const float*)d_in[4];
    const float* dt_w   = (const float*)d_in[5];
    const float* dt_b   = (const float*)d_in[6];
    const float* A_log  = (const float*)d_in[7];
    const float* Dp     = (const float*)d_in[8];
    const float* out_w  = (const float*)d_in[9];
    const float* ln_g   = (const float*)d_in[10];
    const float* ln_b   = (const float*)d_in[11];
    const float* head_w = (const float*)d_in[12];
    const float* head_b = (const float*)d_in[13];
    const int*   ids    = (const int*)d_in[14];

    float* out_logits = (float*)d_out;
    float* out_hidden = (float*)d_out + (size_t)M_ROWS * VOCAB;

    char* base = (char*)d_ws;
    float* x    = (float*)(base);
    bf16*  xr   = (bf16*)(base + 3145728);
    bf16*  R    = (bf16*)(base + 3145728 + 6291456);
    bf16*  dlt  = (bf16*)(base + 3145728 + 6291456 + 3145728);
    bf16*  xdbl = (bf16*)(base + 3145728 + 6291456 + 3145728 + 3145728);

    embed_kernel<<<(M_ROWS * D_MODEL + 255) / 256, 256, 0, stream>>>(emb, ids, x);

    for (int i = 0; i < N_LAYERS; i++) {
        const float* in_w_i   = in_w   + (size_t)i * 2 * D_INNER * D_MODEL;
        const float* conv_w_i = conv_w + (size_t)i * D_INNER * D_CONV;
        const float* conv_b_i = conv_b + (size_t)i * D_INNER;
        const float* xp_w_i   = xp_w   + (size_t)i * XDBL_C * D_INNER;
        const float* dt_w_i   = dt_w   + (size_t)i * D_INNER * DT_RANK;
        const float* dt_b_i   = dt_b   + (size_t)i * D_INNER;
        const float* A_log_i  = A_log  + (size_t)i * D_INNER * D_STATE;
        const float* Dp_i     = Dp     + (size_t)i * D_INNER;
        const float* out_w_i  = out_w  + (size_t)i * D_MODEL * D_INNER;

        // xr = x @ in_w^T  [1024, 3072] bf16
        gemm_mfma<<<dim3(2 * D_INNER / GBN, M_ROWS / GBM), 256, 0, stream>>>(
            x, D_MODEL, 1, in_w_i, D_MODEL, nullptr, nullptr, nullptr, xr,
            M_ROWS, 2 * D_INNER, D_MODEL, 0);

        // R = u = silu(conv(xr[:, :1536]) + conv_b)
        conv_silu_kernel<<<(M_ROWS * D_INNER + 255) / 256, 256, 0, stream>>>(
            xr, conv_w_i, conv_b_i, R);

        // xdbl = R @ xp_w^T  [1024, 80] bf16
        gemm_mfma<<<dim3((XDBL_C + GBN - 1) / GBN, M_ROWS / GBM), 256, 0, stream>>>(
            R, D_INNER, 0, xp_w_i, D_INNER, nullptr, nullptr, nullptr, xdbl,
            M_ROWS, XDBL_C, D_INNER, 0);

        // dlt = softplus(xdbl[:, :48] @ dt_w^T + dt_b)  [1024, 1536] bf16
        gemm_mfma<<<dim3(D_INNER / GBN, M_ROWS / GBM), 256, 0, stream>>>(
            xdbl, XDBL_C, 0, dt_w_i, DT_RANK, dt_b_i, nullptr, nullptr, dlt,
            M_ROWS, D_INNER, DT_RANK, 1);

        // scan + gate fused; g -> xr[:, 0:1536]
        scan_chunked<<<B_SZ * (D_INNER / SDG), 256, 0, stream>>>(
            dlt, R, xdbl, xr, A_log_i, Dp_i);

        // x = g @ out_w^T + x   (A = xr cols 0..1535, lda 3072)
        gemm_mfma<<<dim3(D_MODEL / GBN, M_ROWS / GBM), 256, 0, stream>>>(
            xr, 2 * D_INNER, 0, out_w_i, D_INNER, nullptr, x, x, nullptr,
            M_ROWS, D_MODEL, D_INNER, 0);
    }

    ln_kernel<<<M_ROWS, 256, 0, stream>>>(x, ln_g, ln_b, out_hidden);

    gemm_mfma<<<dim3(VOCAB / GBN, M_ROWS / GBM), 256, 0, stream>>>(
        out_hidden, D_MODEL, 1, head_w, D_MODEL, head_b, nullptr, out_logits, nullptr,
        M_ROWS, VOCAB, D_MODEL, 0);
}